// Round 2
// baseline (154.428 us; speedup 1.0000x reference)
//
#include <hip/hip_runtime.h>

constexpr int Bn = 8, S = 2048, E = 1024, H = 64;
// E^-0.5 * log2(e) folded into q: scores come out of QK^T already in log2
// domain, so softmax is exp2f(s - m) with no per-element LOG2E multiply.
constexpr float SCALE = 0.03125f * 1.44269504f;

typedef __attribute__((ext_vector_type(8))) short short8;  // 8 bf16
typedef __attribute__((ext_vector_type(4))) float f32x4;   // MFMA C/D

__device__ __forceinline__ unsigned short f2bf(float f) {
  unsigned u = __builtin_bit_cast(unsigned, f);
  u += 0x7fffu + ((u >> 16) & 1u);    // RNE
  return (unsigned short)(u >> 16);
}
__device__ __forceinline__ ushort4 f4bf(float4 f) {
  return make_ushort4(f2bf(f.x), f2bf(f.y), f2bf(f.z), f2bf(f.w));
}

// ---------- W [1024][64] fp32 -> WT3 [3][64][1024] bf16 ----------
__global__ __launch_bounds__(256) void wtrans_kernel(
    const float* __restrict__ Wq, const float* __restrict__ Wk,
    const float* __restrict__ Wv, unsigned short* __restrict__ WT3) {
  __shared__ unsigned short tb[64][72];
  const int m = blockIdx.x >> 4;
  const int e0 = (blockIdx.x & 15) * 64;
  const float* W = (m == 0) ? Wq : (m == 1) ? Wk : Wv;
  const int t = threadIdx.x;
#pragma unroll
  for (int it = 0; it < 4; ++it) {
    int idx = t + it * 256;
    int r = idx >> 4, c4 = idx & 15;
    float4 f = ((const float4*)(W + (long)(e0 + r) * H))[c4];
    *(ushort4*)&tb[r][c4 * 4] = f4bf(f);
  }
  __syncthreads();
#pragma unroll
  for (int it = 0; it < 4; ++it) {
    int idx = t + it * 256;
    int h = idx >> 4, e4 = idx & 15;
    ushort4 u = make_ushort4(tb[e4 * 4 + 0][h], tb[e4 * 4 + 1][h],
                             tb[e4 * 4 + 2][h], tb[e4 * 4 + 3][h]);
    ((ushort4*)(WT3 + (long)(m * 64 + h) * E + e0))[e4] = u;
  }
}

// ---------- QKV GEMM, m97-style: M=32 x N=192, BK=128, LDS-dense ----------
__global__ __launch_bounds__(256) void qkv_kernel(
    const float* __restrict__ x, const unsigned short* __restrict__ WT3,
    unsigned short* __restrict__ q, unsigned short* __restrict__ kk,
    unsigned short* __restrict__ vT) {
  __shared__ unsigned short xs[32][136];    // [seq-row][e in chunk]
  __shared__ unsigned short ws[192][136];   // [out-col j][e in chunk]
  const int t = threadIdx.x;
  const int w = t >> 6, lane = t & 63, l15 = lane & 15, g = lane >> 4;
  const long row0 = (long)blockIdx.x * 32;
  const int xrow = t >> 5, xslot = t & 31;  // x: 8 rows x 32 float4 / iter
  const int wrow = t >> 4, wslot = t & 15;  // W: 16 rows x 16 short8 / iter

  f32x4 acc[2][3];
#pragma unroll
  for (int rt = 0; rt < 2; ++rt)
#pragma unroll
    for (int ct = 0; ct < 3; ++ct) acc[rt][ct] = f32x4{0.f, 0.f, 0.f, 0.f};

  float4 px[4];
  short8 pw[12];
  // prologue: chunk 0 -> regs -> LDS
#pragma unroll
  for (int it = 0; it < 4; ++it)
    px[it] = ((const float4*)(x + (row0 + xrow + it * 8) * E))[xslot];
#pragma unroll
  for (int it = 0; it < 12; ++it)
    pw[it] = *(const short8*)(WT3 + (long)(wrow + it * 16) * E + wslot * 8);
#pragma unroll
  for (int it = 0; it < 4; ++it)
    *(ushort4*)&xs[xrow + it * 8][xslot * 4] = f4bf(px[it]);
#pragma unroll
  for (int it = 0; it < 12; ++it)
    *(short8*)&ws[wrow + it * 16][wslot * 8] = pw[it];

  for (int c = 0; c < 8; ++c) {             // 8 chunks of 128 e
    __syncthreads();                        // staged chunk visible
    if (c < 7) {                            // dense prefetch of chunk c+1
      const int e0 = (c + 1) * 128;
#pragma unroll
      for (int it = 0; it < 4; ++it)
        px[it] = ((const float4*)(x + (row0 + xrow + it * 8) * E + e0))[xslot];
#pragma unroll
      for (int it = 0; it < 12; ++it)
        pw[it] = *(const short8*)(WT3 + (long)(wrow + it * 16) * E + e0 + wslot * 8);
    }
#pragma unroll
    for (int kh = 0; kh < 4; ++kh) {
      short8 a0 = *(const short8*)&xs[l15][kh * 32 + g * 8];
      short8 a1 = *(const short8*)&xs[16 + l15][kh * 32 + g * 8];
#pragma unroll
      for (int ct = 0; ct < 3; ++ct) {
        short8 b = *(const short8*)&ws[w * 48 + ct * 16 + l15][kh * 32 + g * 8];
        acc[0][ct] = __builtin_amdgcn_mfma_f32_16x16x32_bf16(a0, b, acc[0][ct], 0, 0, 0);
        acc[1][ct] = __builtin_amdgcn_mfma_f32_16x16x32_bf16(a1, b, acc[1][ct], 0, 0, 0);
      }
    }
    __syncthreads();                        // LDS reads done
    if (c < 7) {
#pragma unroll
      for (int it = 0; it < 4; ++it)
        *(ushort4*)&xs[xrow + it * 8][xslot * 4] = f4bf(px[it]);
#pragma unroll
      for (int it = 0; it < 12; ++it)
        *(short8*)&ws[wrow + it * 16][wslot * 8] = pw[it];
    }
  }

  const int bb = (int)(row0 >> 11);
  const int srow = (int)(row0 & 2047);
#pragma unroll
  for (int ct = 0; ct < 3; ++ct) {
    const int col = w * 48 + ct * 16 + l15;
    const int mm = col >> 6, ch = col & 63;
#pragma unroll
    for (int rt = 0; rt < 2; ++rt) {
      const int srl = rt * 16 + g * 4;
      if (mm == 0) {
#pragma unroll
        for (int r = 0; r < 4; ++r)
          q[(row0 + srl + r) * H + ch] = f2bf(acc[rt][ct][r] * SCALE);
      } else if (mm == 1) {
#pragma unroll
        for (int r = 0; r < 4; ++r)
          kk[(row0 + srl + r) * H + ch] = f2bf(acc[rt][ct][r]);
      } else {
        ushort4 v4 = make_ushort4(f2bf(acc[rt][ct][0]), f2bf(acc[rt][ct][1]),
                                  f2bf(acc[rt][ct][2]), f2bf(acc[rt][ct][3]));
        *(ushort4*)(vT + ((long)bb * H + ch) * S + srow + srl) = v4;
      }
    }
  }
}

// ---------- causal flash attention, S^T form, QBLK=32 rows per wave ------
// attn is L2-BW-bound: per tile-pass a wave reads a full 16KB K+V tile.
// Doubling the q-rows amortized per tile (16 -> 32, two n-frags sharing the
// same ak/av registers) halves K/V L2 traffic (270 -> 135 MB). Block = 512
// thr / 8 waves = two q-groups {p, 63-p} (uniform ~33 tile-units/block,
// each SIMD hosts one long + one short wave); within a group 4 waves split
// keys stride-4. Grid 256 = 1 block/CU = 2 waves/SIMD (unchanged occ).
// Merge: per-group 4-way via LDS atomicAdd accumulator.
__global__ __launch_bounds__(512, 2) void attn_kernel(
    const unsigned short* __restrict__ q, const unsigned short* __restrict__ k,
    const unsigned short* __restrict__ vT, float* __restrict__ out) {
  __shared__ unsigned short pl[8][16][72];  // per-wave P^T [qrow][key]
  __shared__ float Oacc[2][32][68];         // merged O [grp][qrow][h] (+pad)
  __shared__ float ms[2][4][32], ls[2][4][32];
  const int t = threadIdx.x;
  const int w = t >> 6, lane = t & 63, l15 = lane & 15, g = lane >> 4;
  const int grp = w >> 2, w4 = w & 3;       // q-group, key-split index
  const int b = blockIdx.x & 7, p = blockIdx.x >> 3;  // p in 0..31
  const int qg = grp ? (63 - p) : p;        // 32-row q-group id
  const int nt = (qg >> 1) + 1;             // K64 tiles covering keys<=rows
  const int qrow0 = qg * 32;
  const unsigned short* kb = k + (long)b * S * H;
  const unsigned short* vb = vT + (long)b * H * S;

  // zero merge accumulator (ordered before the atomics by the merge barrier)
  for (int i = t; i < 2 * 32 * 68; i += 512) ((float*)Oacc)[i] = 0.f;

  short8 bq[2][2];                          // Q B-frags for both 16-row subtiles
#pragma unroll
  for (int s = 0; s < 2; ++s) {
    const unsigned short* qp = q + ((long)b * S + qrow0 + s * 16 + l15) * H + g * 8;
    bq[s][0] = *(const short8*)qp;
    bq[s][1] = *(const short8*)(qp + 32);
  }
  f32x4 O[2][4];
  float m_[2] = {-1e30f, -1e30f}, l_[2] = {0.f, 0.f};
#pragma unroll
  for (int s = 0; s < 2; ++s)
#pragma unroll
    for (int c = 0; c < 4; ++c) O[s][c] = f32x4{0.f, 0.f, 0.f, 0.f};

  short8 ak[4][2];
  int kt = w4;
  if (kt < nt) {                            // prologue K frags
#pragma unroll
    for (int c = 0; c < 4; ++c)
#pragma unroll
      for (int kh = 0; kh < 2; ++kh)
        ak[c][kh] = *(const short8*)(kb + (long)(kt * 64 + c * 16 + l15) * H + kh * 32 + g * 8);
  }

  for (; kt < nt; kt += 4) {
    // V^T A-frags issued early, shared by both subtiles
    short8 av[4][2];
#pragma unroll
    for (int c = 0; c < 4; ++c)
#pragma unroll
      for (int kh = 0; kh < 2; ++kh)
        av[c][kh] = *(const short8*)(vb + (long)(c * 16 + l15) * S + kt * 64 + kh * 32 + g * 8);
    const bool last = (kt == nt - 1);
#pragma unroll
    for (int s = 0; s < 2; ++s) {
      // ---- S^T = K Q^T : D[m=key][n=qrow], already in log2 units ----
      f32x4 sc[4];
#pragma unroll
      for (int c = 0; c < 4; ++c) {
        sc[c] = f32x4{0.f, 0.f, 0.f, 0.f};
        sc[c] = __builtin_amdgcn_mfma_f32_16x16x32_bf16(ak[c][0], bq[s][0], sc[c], 0, 0, 0);
        sc[c] = __builtin_amdgcn_mfma_f32_16x16x32_bf16(ak[c][1], bq[s][1], sc[c], 0, 0, 0);
      }
      if (s == 1 && kt + 4 < nt) {          // ak dead after subtile-1 QK^T
#pragma unroll
        for (int c = 0; c < 4; ++c)
#pragma unroll
          for (int kh = 0; kh < 2; ++kh)
            ak[c][kh] = *(const short8*)(kb + (long)((kt + 4) * 64 + c * 16 + l15) * H + kh * 32 + g * 8);
      }
      if (last) {                           // diagonal tile: mask key > qrow
#pragma unroll
        for (int c = 0; c < 4; ++c)
#pragma unroll
          for (int r = 0; r < 4; ++r)
            if (kt * 64 + c * 16 + g * 4 + r > qrow0 + s * 16 + l15) sc[c][r] = -1e30f;
      }
      // ---- per-lane softmax: local ops + 2 shuffles each for max/sum ----
      float mx = -1e30f;
#pragma unroll
      for (int c = 0; c < 4; ++c)
#pragma unroll
        for (int r = 0; r < 4; ++r) mx = fmaxf(mx, sc[c][r]);
      mx = fmaxf(mx, __shfl_xor(mx, 16));
      mx = fmaxf(mx, __shfl_xor(mx, 32));
      float mn = fmaxf(m_[s], mx);
      float al = exp2f(m_[s] - mn);
      float sum = 0.f;
#pragma unroll
      for (int c = 0; c < 4; ++c)
#pragma unroll
        for (int r = 0; r < 4; ++r) {
          float pe = exp2f(sc[c][r] - mn);
          sc[c][r] = pe;
          sum += pe;
        }
      sum += __shfl_xor(sum, 16);
      sum += __shfl_xor(sum, 32);
      l_[s] = l_[s] * al + sum;
      m_[s] = mn;
      // ---- P^T -> per-wave LDS, O *= al, O += V^T P^T ----
#pragma unroll
      for (int c = 0; c < 4; ++c) {
        ushort4 p4 = make_ushort4(f2bf(sc[c][0]), f2bf(sc[c][1]),
                                  f2bf(sc[c][2]), f2bf(sc[c][3]));
        *(ushort4*)&pl[w][l15][c * 16 + g * 4] = p4;
      }
#pragma unroll
      for (int c = 0; c < 4; ++c)
#pragma unroll
        for (int r = 0; r < 4; ++r) O[s][c][r] *= al;
      short8 bp0 = *(const short8*)&pl[w][l15][g * 8];
      short8 bp1 = *(const short8*)&pl[w][l15][32 + g * 8];
#pragma unroll
      for (int c = 0; c < 4; ++c) {
        O[s][c] = __builtin_amdgcn_mfma_f32_16x16x32_bf16(av[c][0], bp0, O[s][c], 0, 0, 0);
        O[s][c] = __builtin_amdgcn_mfma_f32_16x16x32_bf16(av[c][1], bp1, O[s][c], 0, 0, 0);
      }
    }
  }

  // ---- 4-way merge per q-group ----
  if (g == 0) {
    ms[grp][w4][l15]      = m_[0];  ls[grp][w4][l15]      = l_[0];
    ms[grp][w4][16 + l15] = m_[1];  ls[grp][w4][16 + l15] = l_[1];
  }
  __syncthreads();
#pragma unroll
  for (int s = 0; s < 2; ++s) {
    const int row = s * 16 + l15;
    float mm0 = ms[grp][0][row], mm1 = ms[grp][1][row];
    float mm2 = ms[grp][2][row], mm3 = ms[grp][3][row];
    float mstar = fmaxf(fmaxf(mm0, mm1), fmaxf(mm2, mm3));
    float f = exp2f(m_[s] - mstar);
#pragma unroll
    for (int c = 0; c < 4; ++c)
#pragma unroll
      for (int r = 0; r < 4; ++r)
        atomicAdd(&Oacc[grp][row][c * 16 + g * 4 + r], O[s][c][r] * f);
  }
  __syncthreads();
  // ---- normalized output: 2 groups x 32 rows x 64 h ----
  {
    const int g2 = t >> 8, t256 = t & 255;
    const int row = t256 >> 3, h0 = (t256 & 7) * 8;
    const int qgo = g2 ? (63 - p) : p;
    float mm0 = ms[g2][0][row], mm1 = ms[g2][1][row];
    float mm2 = ms[g2][2][row], mm3 = ms[g2][3][row];
    float mstar = fmaxf(fmaxf(mm0, mm1), fmaxf(mm2, mm3));
    float lsum = ls[g2][0][row] * exp2f(mm0 - mstar) +
                 ls[g2][1][row] * exp2f(mm1 - mstar) +
                 ls[g2][2][row] * exp2f(mm2 - mstar) +
                 ls[g2][3][row] * exp2f(mm3 - mstar);
    float inv = 1.0f / lsum;
    float* op = out + ((long)b * S + qgo * 32 + row) * H + h0;
    float4 o0, o1;
    o0.x = Oacc[g2][row][h0 + 0] * inv;  o0.y = Oacc[g2][row][h0 + 1] * inv;
    o0.z = Oacc[g2][row][h0 + 2] * inv;  o0.w = Oacc[g2][row][h0 + 3] * inv;
    o1.x = Oacc[g2][row][h0 + 4] * inv;  o1.y = Oacc[g2][row][h0 + 5] * inv;
    o1.z = Oacc[g2][row][h0 + 6] * inv;  o1.w = Oacc[g2][row][h0 + 7] * inv;
    *(float4*)op = o0;
    *(float4*)(op + 4) = o1;
  }
}

extern "C" void kernel_launch(void* const* d_in, const int* in_sizes, int n_in,
                              void* d_out, int out_size, void* d_ws, size_t ws_size,
                              hipStream_t stream) {
  const float* x  = (const float*)d_in[0];
  const float* Wq = (const float*)d_in[1];
  const float* Wk = (const float*)d_in[2];
  const float* Wv = (const float*)d_in[3];
  float* outp = (float*)d_out;
  unsigned short* WT3 = (unsigned short*)d_ws;                       // 384 KB
  unsigned short* q  = (unsigned short*)((char*)d_ws + 512 * 1024);  // 2 MB each
  unsigned short* kk = q + (size_t)Bn * S * H;
  unsigned short* vT = kk + (size_t)Bn * S * H;
  wtrans_kernel<<<dim3(48), dim3(256), 0, stream>>>(Wq, Wk, Wv, WT3);
  qkv_kernel<<<dim3((Bn * S) / 32), dim3(256), 0, stream>>>(x, WT3, q, kk, vT);
  attn_kernel<<<dim3(Bn * 32), dim3(512), 0, stream>>>(q, kk, vT, outp);
}

// Round 3
// 153.289 us; speedup vs baseline: 1.0074x; 1.0074x over previous
//
#include <hip/hip_runtime.h>

constexpr int Bn = 8, S = 2048, E = 1024, H = 64;
// E^-0.5 * log2(e) folded into q: scores come out of QK^T already in log2
// domain, so softmax is exp2f(s - m) with no per-element LOG2E multiply.
constexpr float SCALE = 0.03125f * 1.44269504f;

typedef __attribute__((ext_vector_type(8))) short short8;  // 8 bf16
typedef __attribute__((ext_vector_type(4))) float f32x4;   // MFMA C/D

__device__ __forceinline__ unsigned short f2bf(float f) {
  unsigned u = __builtin_bit_cast(unsigned, f);
  u += 0x7fffu + ((u >> 16) & 1u);    // RNE
  return (unsigned short)(u >> 16);
}
__device__ __forceinline__ ushort4 f4bf(float4 f) {
  return make_ushort4(f2bf(f.x), f2bf(f.y), f2bf(f.z), f2bf(f.w));
}

// ---------- W [1024][64] fp32 -> WT3 [3][64][1024] bf16 ----------
__global__ __launch_bounds__(256) void wtrans_kernel(
    const float* __restrict__ Wq, const float* __restrict__ Wk,
    const float* __restrict__ Wv, unsigned short* __restrict__ WT3) {
  __shared__ unsigned short tb[64][72];
  const int m = blockIdx.x >> 4;
  const int e0 = (blockIdx.x & 15) * 64;
  const float* W = (m == 0) ? Wq : (m == 1) ? Wk : Wv;
  const int t = threadIdx.x;
#pragma unroll
  for (int it = 0; it < 4; ++it) {
    int idx = t + it * 256;
    int r = idx >> 4, c4 = idx & 15;
    float4 f = ((const float4*)(W + (long)(e0 + r) * H))[c4];
    *(ushort4*)&tb[r][c4 * 4] = f4bf(f);
  }
  __syncthreads();
#pragma unroll
  for (int it = 0; it < 4; ++it) {
    int idx = t + it * 256;
    int h = idx >> 4, e4 = idx & 15;
    ushort4 u = make_ushort4(tb[e4 * 4 + 0][h], tb[e4 * 4 + 1][h],
                             tb[e4 * 4 + 2][h], tb[e4 * 4 + 3][h]);
    ((ushort4*)(WT3 + (long)(m * 64 + h) * E + e0))[e4] = u;
  }
}

// ---------- QKV GEMM, m97-style: M=32 x N=192, BK=128, LDS-dense ----------
__global__ __launch_bounds__(256) void qkv_kernel(
    const float* __restrict__ x, const unsigned short* __restrict__ WT3,
    unsigned short* __restrict__ q, unsigned short* __restrict__ kk,
    unsigned short* __restrict__ vT) {
  __shared__ unsigned short xs[32][136];    // [seq-row][e in chunk]
  __shared__ unsigned short ws[192][136];   // [out-col j][e in chunk]
  const int t = threadIdx.x;
  const int w = t >> 6, lane = t & 63, l15 = lane & 15, g = lane >> 4;
  const long row0 = (long)blockIdx.x * 32;
  const int xrow = t >> 5, xslot = t & 31;  // x: 8 rows x 32 float4 / iter
  const int wrow = t >> 4, wslot = t & 15;  // W: 16 rows x 16 short8 / iter

  f32x4 acc[2][3];
#pragma unroll
  for (int rt = 0; rt < 2; ++rt)
#pragma unroll
    for (int ct = 0; ct < 3; ++ct) acc[rt][ct] = f32x4{0.f, 0.f, 0.f, 0.f};

  float4 px[4];
  short8 pw[12];
  // prologue: chunk 0 -> regs -> LDS
#pragma unroll
  for (int it = 0; it < 4; ++it)
    px[it] = ((const float4*)(x + (row0 + xrow + it * 8) * E))[xslot];
#pragma unroll
  for (int it = 0; it < 12; ++it)
    pw[it] = *(const short8*)(WT3 + (long)(wrow + it * 16) * E + wslot * 8);
#pragma unroll
  for (int it = 0; it < 4; ++it)
    *(ushort4*)&xs[xrow + it * 8][xslot * 4] = f4bf(px[it]);
#pragma unroll
  for (int it = 0; it < 12; ++it)
    *(short8*)&ws[wrow + it * 16][wslot * 8] = pw[it];

  for (int c = 0; c < 8; ++c) {             // 8 chunks of 128 e
    __syncthreads();                        // staged chunk visible
    if (c < 7) {                            // dense prefetch of chunk c+1
      const int e0 = (c + 1) * 128;
#pragma unroll
      for (int it = 0; it < 4; ++it)
        px[it] = ((const float4*)(x + (row0 + xrow + it * 8) * E + e0))[xslot];
#pragma unroll
      for (int it = 0; it < 12; ++it)
        pw[it] = *(const short8*)(WT3 + (long)(wrow + it * 16) * E + e0 + wslot * 8);
    }
#pragma unroll
    for (int kh = 0; kh < 4; ++kh) {
      short8 a0 = *(const short8*)&xs[l15][kh * 32 + g * 8];
      short8 a1 = *(const short8*)&xs[16 + l15][kh * 32 + g * 8];
#pragma unroll
      for (int ct = 0; ct < 3; ++ct) {
        short8 b = *(const short8*)&ws[w * 48 + ct * 16 + l15][kh * 32 + g * 8];
        acc[0][ct] = __builtin_amdgcn_mfma_f32_16x16x32_bf16(a0, b, acc[0][ct], 0, 0, 0);
        acc[1][ct] = __builtin_amdgcn_mfma_f32_16x16x32_bf16(a1, b, acc[1][ct], 0, 0, 0);
      }
    }
    __syncthreads();                        // LDS reads done
    if (c < 7) {
#pragma unroll
      for (int it = 0; it < 4; ++it)
        *(ushort4*)&xs[xrow + it * 8][xslot * 4] = f4bf(px[it]);
#pragma unroll
      for (int it = 0; it < 12; ++it)
        *(short8*)&ws[wrow + it * 16][wslot * 8] = pw[it];
    }
  }

  const int bb = (int)(row0 >> 11);
  const int srow = (int)(row0 & 2047);
#pragma unroll
  for (int ct = 0; ct < 3; ++ct) {
    const int col = w * 48 + ct * 16 + l15;
    const int mm = col >> 6, ch = col & 63;
#pragma unroll
    for (int rt = 0; rt < 2; ++rt) {
      const int srl = rt * 16 + g * 4;
      if (mm == 0) {
#pragma unroll
        for (int r = 0; r < 4; ++r)
          q[(row0 + srl + r) * H + ch] = f2bf(acc[rt][ct][r] * SCALE);
      } else if (mm == 1) {
#pragma unroll
        for (int r = 0; r < 4; ++r)
          kk[(row0 + srl + r) * H + ch] = f2bf(acc[rt][ct][r]);
      } else {
        ushort4 v4 = make_ushort4(f2bf(acc[rt][ct][0]), f2bf(acc[rt][ct][1]),
                                  f2bf(acc[rt][ct][2]), f2bf(acc[rt][ct][3]));
        *(ushort4*)(vT + ((long)bb * H + ch) * S + srow + srl) = v4;
      }
    }
  }
}

// ---------- causal flash attention: 1 q-tile (16 rows) per block ---------
// Diagnosis (r2 counters): MfmaUtil 3.6%, VALUBusy 16.5%, Occupancy 19.5%
// -> latency-bound, waves mostly stalled; grid size capped waves/CU at 8.
// Fix: maximize block count + occupancy. Block = 256 thr / 4 waves owns ONE
// 16-row q-tile; waves split the K64-tile list stride-4 (balanced: worst
// wave 8 tiles at qt=127); in-block 4-way LDS merge (no atomics, no cross-
// block merge). Grid = 8b x 128qt = 1024, longest-qt-first for backfill.
// Registers trimmed (single phase: bq 8 + O 16 + ak 32 + av 32 + sc 16)
// to fit launch_bounds(256,4) -> 16 waves/CU, 2x round-1. Tree max/sum
// reductions (depth 4 vs 16-deep chains) shorten the serial softmax path.
__global__ __launch_bounds__(256, 4) void attn_kernel(
    const unsigned short* __restrict__ q, const unsigned short* __restrict__ k,
    const unsigned short* __restrict__ vT, float* __restrict__ out) {
  __shared__ unsigned short pl[4][16][72];  // per-wave P^T [qrow][key]
  __shared__ float Om[4][64][17];           // partial O^T [wave][h][qrow]
  __shared__ float ms[4][16], ls[4][16];
  const int t = threadIdx.x;
  const int w = t >> 6, lane = t & 63, l15 = lane & 15, g = lane >> 4;
  const int b = blockIdx.x & 7, p = blockIdx.x >> 3;
  const int qt = 127 - p;                   // longest blocks dispatch first
  const int qrow0 = qt * 16;
  const int nt = (qt >> 2) + 1;             // K64 tiles covering keys<=rows
  const unsigned short* kb = k + (long)b * S * H;
  const unsigned short* vb = vT + (long)b * H * S;

  const unsigned short* qp = q + ((long)b * S + qrow0 + l15) * H + g * 8;
  short8 bq0 = *(const short8*)qp;          // Q B-frags: n=l15=qrow, k=h
  short8 bq1 = *(const short8*)(qp + 32);

  f32x4 O[4];
#pragma unroll
  for (int c = 0; c < 4; ++c) O[c] = f32x4{0.f, 0.f, 0.f, 0.f};
  float m_ = -1e30f, l_ = 0.f;

  short8 ak[4][2];
  int kt = w;                               // wave w: tiles kt == w (mod 4)
  if (kt < nt) {                            // prologue K frags
#pragma unroll
    for (int c = 0; c < 4; ++c)
#pragma unroll
      for (int kh = 0; kh < 2; ++kh)
        ak[c][kh] = *(const short8*)(kb + (long)(kt * 64 + c * 16 + l15) * H + kh * 32 + g * 8);
  }

  for (; kt < nt; kt += 4) {
    // V^T A-frags issued early (consumed at the end of the iteration)
    short8 av[4][2];
#pragma unroll
    for (int c = 0; c < 4; ++c)
#pragma unroll
      for (int kh = 0; kh < 2; ++kh)
        av[c][kh] = *(const short8*)(vb + (long)(c * 16 + l15) * S + kt * 64 + kh * 32 + g * 8);
    // ---- S^T = K Q^T : D[m=key][n=qrow], already in log2 units ----
    f32x4 sc[4];
#pragma unroll
    for (int c = 0; c < 4; ++c) {
      sc[c] = f32x4{0.f, 0.f, 0.f, 0.f};
      sc[c] = __builtin_amdgcn_mfma_f32_16x16x32_bf16(ak[c][0], bq0, sc[c], 0, 0, 0);
      sc[c] = __builtin_amdgcn_mfma_f32_16x16x32_bf16(ak[c][1], bq1, sc[c], 0, 0, 0);
    }
    // prefetch K frags for kt+4
    if (kt + 4 < nt) {
#pragma unroll
      for (int c = 0; c < 4; ++c)
#pragma unroll
        for (int kh = 0; kh < 2; ++kh)
          ak[c][kh] = *(const short8*)(kb + (long)((kt + 4) * 64 + c * 16 + l15) * H + kh * 32 + g * 8);
    }
    if (kt == nt - 1) {                     // diagonal tile: mask key > qrow
#pragma unroll
      for (int c = 0; c < 4; ++c)
#pragma unroll
        for (int r = 0; r < 4; ++r)
          if (kt * 64 + c * 16 + g * 4 + r > qrow0 + l15) sc[c][r] = -1e30f;
    }
    // ---- per-lane softmax: tree reduce (depth 4) + 2 shuffles ----
    float x0 = fmaxf(fmaxf(sc[0][0], sc[0][1]), fmaxf(sc[0][2], sc[0][3]));
    float x1 = fmaxf(fmaxf(sc[1][0], sc[1][1]), fmaxf(sc[1][2], sc[1][3]));
    float x2 = fmaxf(fmaxf(sc[2][0], sc[2][1]), fmaxf(sc[2][2], sc[2][3]));
    float x3 = fmaxf(fmaxf(sc[3][0], sc[3][1]), fmaxf(sc[3][2], sc[3][3]));
    float mx = fmaxf(fmaxf(x0, x1), fmaxf(x2, x3));
    mx = fmaxf(mx, __shfl_xor(mx, 16));
    mx = fmaxf(mx, __shfl_xor(mx, 32));
    float mn = fmaxf(m_, mx);
    float al = exp2f(m_ - mn);
#pragma unroll
    for (int c = 0; c < 4; ++c)
#pragma unroll
      for (int r = 0; r < 4; ++r) sc[c][r] = exp2f(sc[c][r] - mn);
    float s0 = (sc[0][0] + sc[0][1]) + (sc[0][2] + sc[0][3]);
    float s1 = (sc[1][0] + sc[1][1]) + (sc[1][2] + sc[1][3]);
    float s2 = (sc[2][0] + sc[2][1]) + (sc[2][2] + sc[2][3]);
    float s3 = (sc[3][0] + sc[3][1]) + (sc[3][2] + sc[3][3]);
    float sum = (s0 + s1) + (s2 + s3);
    sum += __shfl_xor(sum, 16);
    sum += __shfl_xor(sum, 32);
    l_ = l_ * al + sum;
    m_ = mn;
    // ---- P^T -> per-wave LDS, O *= al ----
#pragma unroll
    for (int c = 0; c < 4; ++c) {
      ushort4 p4 = make_ushort4(f2bf(sc[c][0]), f2bf(sc[c][1]),
                                f2bf(sc[c][2]), f2bf(sc[c][3]));
      *(ushort4*)&pl[w][l15][c * 16 + g * 4] = p4;
    }
#pragma unroll
    for (int c = 0; c < 4; ++c)
#pragma unroll
      for (int r = 0; r < 4; ++r) O[c][r] *= al;
    // ---- O^T += V^T P^T ----
    short8 bp0 = *(const short8*)&pl[w][l15][g * 8];
    short8 bp1 = *(const short8*)&pl[w][l15][32 + g * 8];
#pragma unroll
    for (int c = 0; c < 4; ++c) {
      O[c] = __builtin_amdgcn_mfma_f32_16x16x32_bf16(av[c][0], bp0, O[c], 0, 0, 0);
      O[c] = __builtin_amdgcn_mfma_f32_16x16x32_bf16(av[c][1], bp1, O[c], 0, 0, 0);
    }
  }

  // ---- 4-way in-block merge ----
  if (g == 0) { ms[w][l15] = m_; ls[w][l15] = l_; }
#pragma unroll
  for (int c = 0; c < 4; ++c)
#pragma unroll
    for (int r = 0; r < 4; ++r)
      Om[w][c * 16 + g * 4 + r][l15] = O[c][r];
  __syncthreads();
  {
    const int row = t >> 4, h0 = (t & 15) * 4;   // 256 thr = 16 rows x 16 h-quads
    float m0 = ms[0][row], m1 = ms[1][row], m2 = ms[2][row], m3 = ms[3][row];
    float mstar = fmaxf(fmaxf(m0, m1), fmaxf(m2, m3));
    float f0 = exp2f(m0 - mstar), f1 = exp2f(m1 - mstar);
    float f2 = exp2f(m2 - mstar), f3 = exp2f(m3 - mstar);
    float inv = 1.0f / (ls[0][row] * f0 + ls[1][row] * f1 +
                        ls[2][row] * f2 + ls[3][row] * f3);
    float4 o;
    o.x = (Om[0][h0 + 0][row] * f0 + Om[1][h0 + 0][row] * f1 +
           Om[2][h0 + 0][row] * f2 + Om[3][h0 + 0][row] * f3) * inv;
    o.y = (Om[0][h0 + 1][row] * f0 + Om[1][h0 + 1][row] * f1 +
           Om[2][h0 + 1][row] * f2 + Om[3][h0 + 1][row] * f3) * inv;
    o.z = (Om[0][h0 + 2][row] * f0 + Om[1][h0 + 2][row] * f1 +
           Om[2][h0 + 2][row] * f2 + Om[3][h0 + 2][row] * f3) * inv;
    o.w = (Om[0][h0 + 3][row] * f0 + Om[1][h0 + 3][row] * f1 +
           Om[2][h0 + 3][row] * f2 + Om[3][h0 + 3][row] * f3) * inv;
    *(float4*)(out + ((long)b * S + qrow0 + row) * H + h0) = o;
  }
}

extern "C" void kernel_launch(void* const* d_in, const int* in_sizes, int n_in,
                              void* d_out, int out_size, void* d_ws, size_t ws_size,
                              hipStream_t stream) {
  const float* x  = (const float*)d_in[0];
  const float* Wq = (const float*)d_in[1];
  const float* Wk = (const float*)d_in[2];
  const float* Wv = (const float*)d_in[3];
  float* outp = (float*)d_out;
  unsigned short* WT3 = (unsigned short*)d_ws;                       // 384 KB
  unsigned short* q  = (unsigned short*)((char*)d_ws + 512 * 1024);  // 2 MB each
  unsigned short* kk = q + (size_t)Bn * S * H;
  unsigned short* vT = kk + (size_t)Bn * S * H;
  wtrans_kernel<<<dim3(48), dim3(256), 0, stream>>>(Wq, Wk, Wv, WT3);
  qkv_kernel<<<dim3((Bn * S) / 32), dim3(256), 0, stream>>>(x, WT3, q, kk, vT);
  attn_kernel<<<dim3(Bn * 128), dim3(256), 0, stream>>>(q, kk, vT, outp);
}

// Round 4
// 144.360 us; speedup vs baseline: 1.0697x; 1.0619x over previous
//
#include <hip/hip_runtime.h>

constexpr int Bn = 8, S = 2048, E = 1024, H = 64;
// E^-0.5 * log2(e) folded into q: scores come out of QK^T already in log2
// domain, so softmax is exp2f(s - m) with no per-element LOG2E multiply.
constexpr float SCALE = 0.03125f * 1.44269504f;

typedef __attribute__((ext_vector_type(8))) short short8;  // 8 bf16
typedef __attribute__((ext_vector_type(4))) float f32x4;   // MFMA C/D

__device__ __forceinline__ unsigned short f2bf(float f) {
  unsigned u = __builtin_bit_cast(unsigned, f);
  u += 0x7fffu + ((u >> 16) & 1u);    // RNE
  return (unsigned short)(u >> 16);
}
__device__ __forceinline__ ushort4 f4bf(float4 f) {
  return make_ushort4(f2bf(f.x), f2bf(f.y), f2bf(f.z), f2bf(f.w));
}

// ---------- W [1024][64] fp32 -> WT3 [3][64][1024] bf16 ----------
__global__ __launch_bounds__(256) void wtrans_kernel(
    const float* __restrict__ Wq, const float* __restrict__ Wk,
    const float* __restrict__ Wv, unsigned short* __restrict__ WT3) {
  __shared__ unsigned short tb[64][72];
  const int m = blockIdx.x >> 4;
  const int e0 = (blockIdx.x & 15) * 64;
  const float* W = (m == 0) ? Wq : (m == 1) ? Wk : Wv;
  const int t = threadIdx.x;
#pragma unroll
  for (int it = 0; it < 4; ++it) {
    int idx = t + it * 256;
    int r = idx >> 4, c4 = idx & 15;
    float4 f = ((const float4*)(W + (long)(e0 + r) * H))[c4];
    *(ushort4*)&tb[r][c4 * 4] = f4bf(f);
  }
  __syncthreads();
#pragma unroll
  for (int it = 0; it < 4; ++it) {
    int idx = t + it * 256;
    int h = idx >> 4, e4 = idx & 15;
    ushort4 u = make_ushort4(tb[e4 * 4 + 0][h], tb[e4 * 4 + 1][h],
                             tb[e4 * 4 + 2][h], tb[e4 * 4 + 3][h]);
    ((ushort4*)(WT3 + (long)(m * 64 + h) * E + e0))[e4] = u;
  }
}

// ---------- QKV GEMM, m97-style: M=32 x N=192, BK=128, LDS-dense ----------
__global__ __launch_bounds__(256) void qkv_kernel(
    const float* __restrict__ x, const unsigned short* __restrict__ WT3,
    unsigned short* __restrict__ q, unsigned short* __restrict__ kk,
    unsigned short* __restrict__ vT) {
  __shared__ unsigned short xs[32][136];    // [seq-row][e in chunk]
  __shared__ unsigned short ws[192][136];   // [out-col j][e in chunk]
  const int t = threadIdx.x;
  const int w = t >> 6, lane = t & 63, l15 = lane & 15, g = lane >> 4;
  const long row0 = (long)blockIdx.x * 32;
  const int xrow = t >> 5, xslot = t & 31;  // x: 8 rows x 32 float4 / iter
  const int wrow = t >> 4, wslot = t & 15;  // W: 16 rows x 16 short8 / iter

  f32x4 acc[2][3];
#pragma unroll
  for (int rt = 0; rt < 2; ++rt)
#pragma unroll
    for (int ct = 0; ct < 3; ++ct) acc[rt][ct] = f32x4{0.f, 0.f, 0.f, 0.f};

  float4 px[4];
  short8 pw[12];
  // prologue: chunk 0 -> regs -> LDS
#pragma unroll
  for (int it = 0; it < 4; ++it)
    px[it] = ((const float4*)(x + (row0 + xrow + it * 8) * E))[xslot];
#pragma unroll
  for (int it = 0; it < 12; ++it)
    pw[it] = *(const short8*)(WT3 + (long)(wrow + it * 16) * E + wslot * 8);
#pragma unroll
  for (int it = 0; it < 4; ++it)
    *(ushort4*)&xs[xrow + it * 8][xslot * 4] = f4bf(px[it]);
#pragma unroll
  for (int it = 0; it < 12; ++it)
    *(short8*)&ws[wrow + it * 16][wslot * 8] = pw[it];

  for (int c = 0; c < 8; ++c) {             // 8 chunks of 128 e
    __syncthreads();                        // staged chunk visible
    if (c < 7) {                            // dense prefetch of chunk c+1
      const int e0 = (c + 1) * 128;
#pragma unroll
      for (int it = 0; it < 4; ++it)
        px[it] = ((const float4*)(x + (row0 + xrow + it * 8) * E + e0))[xslot];
#pragma unroll
      for (int it = 0; it < 12; ++it)
        pw[it] = *(const short8*)(WT3 + (long)(wrow + it * 16) * E + e0 + wslot * 8);
    }
#pragma unroll
    for (int kh = 0; kh < 4; ++kh) {
      short8 a0 = *(const short8*)&xs[l15][kh * 32 + g * 8];
      short8 a1 = *(const short8*)&xs[16 + l15][kh * 32 + g * 8];
#pragma unroll
      for (int ct = 0; ct < 3; ++ct) {
        short8 b = *(const short8*)&ws[w * 48 + ct * 16 + l15][kh * 32 + g * 8];
        acc[0][ct] = __builtin_amdgcn_mfma_f32_16x16x32_bf16(a0, b, acc[0][ct], 0, 0, 0);
        acc[1][ct] = __builtin_amdgcn_mfma_f32_16x16x32_bf16(a1, b, acc[1][ct], 0, 0, 0);
      }
    }
    __syncthreads();                        // LDS reads done
    if (c < 7) {
#pragma unroll
      for (int it = 0; it < 4; ++it)
        *(ushort4*)&xs[xrow + it * 8][xslot * 4] = f4bf(px[it]);
#pragma unroll
      for (int it = 0; it < 12; ++it)
        *(short8*)&ws[wrow + it * 16][wslot * 8] = pw[it];
    }
  }

  const int bb = (int)(row0 >> 11);
  const int srow = (int)(row0 & 2047);
#pragma unroll
  for (int ct = 0; ct < 3; ++ct) {
    const int col = w * 48 + ct * 16 + l15;
    const int mm = col >> 6, ch = col & 63;
#pragma unroll
    for (int rt = 0; rt < 2; ++rt) {
      const int srl = rt * 16 + g * 4;
      if (mm == 0) {
#pragma unroll
        for (int r = 0; r < 4; ++r)
          q[(row0 + srl + r) * H + ch] = f2bf(acc[rt][ct][r] * SCALE);
      } else if (mm == 1) {
#pragma unroll
        for (int r = 0; r < 4; ++r)
          kk[(row0 + srl + r) * H + ch] = f2bf(acc[rt][ct][r]);
      } else {
        ushort4 v4 = make_ushort4(f2bf(acc[rt][ct][0]), f2bf(acc[rt][ct][1]),
                                  f2bf(acc[rt][ct][2]), f2bf(acc[rt][ct][3]));
        *(ushort4*)(vT + ((long)bb * H + ch) * S + srow + srl) = v4;
      }
    }
  }
}

// ---------- causal flash attention: 1 q-tile (16 rows) per block ---------
// r3 post-mortem: __launch_bounds__(256,4) capped VGPR at 128 < ~150 live
// -> allocator reported 64 VGPR and spilled the frag arrays to scratch
// (WRITE_SIZE 11MB vs 4MB true output; MfmaUtil 3%). Fix: (256,2) -> cap
// 256, everything register-resident (~160 VGPR, 2 blocks/CU, 8 waves/CU).
// Chain trim: l_ kept as PER-LANE partial (only m_ must be uniform across
// the 4 g-groups to rescale O) -> the two sum-shuffles leave the loop;
// single +-16/+-32 sum reduce after the loop. Per-pass serial chain loses
// ~120 cyc (2 DS-latency shuffles). Structure: block = 256 thr / 4 waves
// owns ONE 16-row q-tile, waves split K64 tiles stride-4 (worst wave 8
// passes), in-block 4-way LDS merge; grid 1024 longest-first.
__global__ __launch_bounds__(256, 2) void attn_kernel(
    const unsigned short* __restrict__ q, const unsigned short* __restrict__ k,
    const unsigned short* __restrict__ vT, float* __restrict__ out) {
  __shared__ unsigned short pl[4][16][72];  // per-wave P^T [qrow][key]
  __shared__ float Om[4][64][17];           // partial O^T [wave][h][qrow]
  __shared__ float ms[4][16], ls[4][16];
  const int t = threadIdx.x;
  const int w = t >> 6, lane = t & 63, l15 = lane & 15, g = lane >> 4;
  const int b = blockIdx.x & 7, p = blockIdx.x >> 3;
  const int qt = 127 - p;                   // longest blocks dispatch first
  const int qrow0 = qt * 16;
  const int nt = (qt >> 2) + 1;             // K64 tiles covering keys<=rows
  const unsigned short* kb = k + (long)b * S * H;
  const unsigned short* vb = vT + (long)b * H * S;

  const unsigned short* qp = q + ((long)b * S + qrow0 + l15) * H + g * 8;
  short8 bq0 = *(const short8*)qp;          // Q B-frags: n=l15=qrow, k=h
  short8 bq1 = *(const short8*)(qp + 32);

  f32x4 O[4];
#pragma unroll
  for (int c = 0; c < 4; ++c) O[c] = f32x4{0.f, 0.f, 0.f, 0.f};
  float m_ = -1e30f, l_ = 0.f;              // l_ is per-lane partial

  short8 ak[4][2];
  int kt = w;                               // wave w: tiles kt == w (mod 4)
  if (kt < nt) {                            // prologue K frags
#pragma unroll
    for (int c = 0; c < 4; ++c)
#pragma unroll
      for (int kh = 0; kh < 2; ++kh)
        ak[c][kh] = *(const short8*)(kb + (long)(kt * 64 + c * 16 + l15) * H + kh * 32 + g * 8);
  }

  for (; kt < nt; kt += 4) {
    // V^T A-frags issued early (consumed at the end of the iteration)
    short8 av[4][2];
#pragma unroll
    for (int c = 0; c < 4; ++c)
#pragma unroll
      for (int kh = 0; kh < 2; ++kh)
        av[c][kh] = *(const short8*)(vb + (long)(c * 16 + l15) * S + kt * 64 + kh * 32 + g * 8);
    // ---- S^T = K Q^T : D[m=key][n=qrow], already in log2 units ----
    f32x4 sc[4];
#pragma unroll
    for (int c = 0; c < 4; ++c) {
      sc[c] = f32x4{0.f, 0.f, 0.f, 0.f};
      sc[c] = __builtin_amdgcn_mfma_f32_16x16x32_bf16(ak[c][0], bq0, sc[c], 0, 0, 0);
      sc[c] = __builtin_amdgcn_mfma_f32_16x16x32_bf16(ak[c][1], bq1, sc[c], 0, 0, 0);
    }
    // prefetch K frags for kt+4
    if (kt + 4 < nt) {
#pragma unroll
      for (int c = 0; c < 4; ++c)
#pragma unroll
        for (int kh = 0; kh < 2; ++kh)
          ak[c][kh] = *(const short8*)(kb + (long)((kt + 4) * 64 + c * 16 + l15) * H + kh * 32 + g * 8);
    }
    if (kt == nt - 1) {                     // diagonal tile: mask key > qrow
#pragma unroll
      for (int c = 0; c < 4; ++c)
#pragma unroll
        for (int r = 0; r < 4; ++r)
          if (kt * 64 + c * 16 + g * 4 + r > qrow0 + l15) sc[c][r] = -1e30f;
    }
    // ---- softmax: tree max (depth 4) + 2 shuffles; per-lane partial sum --
    float x0 = fmaxf(fmaxf(sc[0][0], sc[0][1]), fmaxf(sc[0][2], sc[0][3]));
    float x1 = fmaxf(fmaxf(sc[1][0], sc[1][1]), fmaxf(sc[1][2], sc[1][3]));
    float x2 = fmaxf(fmaxf(sc[2][0], sc[2][1]), fmaxf(sc[2][2], sc[2][3]));
    float x3 = fmaxf(fmaxf(sc[3][0], sc[3][1]), fmaxf(sc[3][2], sc[3][3]));
    float mx = fmaxf(fmaxf(x0, x1), fmaxf(x2, x3));
    mx = fmaxf(mx, __shfl_xor(mx, 16));
    mx = fmaxf(mx, __shfl_xor(mx, 32));
    float mn = fmaxf(m_, mx);               // uniform across the 4 g-groups
    float al = exp2f(m_ - mn);
#pragma unroll
    for (int c = 0; c < 4; ++c)
#pragma unroll
      for (int r = 0; r < 4; ++r) sc[c][r] = exp2f(sc[c][r] - mn);
    float s0 = (sc[0][0] + sc[0][1]) + (sc[0][2] + sc[0][3]);
    float s1 = (sc[1][0] + sc[1][1]) + (sc[1][2] + sc[1][3]);
    float s2 = (sc[2][0] + sc[2][1]) + (sc[2][2] + sc[2][3]);
    float s3 = (sc[3][0] + sc[3][1]) + (sc[3][2] + sc[3][3]);
    l_ = l_ * al + ((s0 + s1) + (s2 + s3)); // per-lane partial; no shuffles
    m_ = mn;
    // ---- P^T -> per-wave LDS, O *= al ----
#pragma unroll
    for (int c = 0; c < 4; ++c) {
      ushort4 p4 = make_ushort4(f2bf(sc[c][0]), f2bf(sc[c][1]),
                                f2bf(sc[c][2]), f2bf(sc[c][3]));
      *(ushort4*)&pl[w][l15][c * 16 + g * 4] = p4;
    }
#pragma unroll
    for (int c = 0; c < 4; ++c)
#pragma unroll
      for (int r = 0; r < 4; ++r) O[c][r] *= al;
    // ---- O^T += V^T P^T ----
    short8 bp0 = *(const short8*)&pl[w][l15][g * 8];
    short8 bp1 = *(const short8*)&pl[w][l15][32 + g * 8];
#pragma unroll
    for (int c = 0; c < 4; ++c) {
      O[c] = __builtin_amdgcn_mfma_f32_16x16x32_bf16(av[c][0], bp0, O[c], 0, 0, 0);
      O[c] = __builtin_amdgcn_mfma_f32_16x16x32_bf16(av[c][1], bp1, O[c], 0, 0, 0);
    }
  }

  // complete the deferred l reduction (sum partials across the 4 g-groups)
  l_ += __shfl_xor(l_, 16);
  l_ += __shfl_xor(l_, 32);

  // ---- 4-way in-block merge ----
  if (g == 0) { ms[w][l15] = m_; ls[w][l15] = l_; }
#pragma unroll
  for (int c = 0; c < 4; ++c)
#pragma unroll
    for (int r = 0; r < 4; ++r)
      Om[w][c * 16 + g * 4 + r][l15] = O[c][r];
  __syncthreads();
  {
    const int row = t >> 4, h0 = (t & 15) * 4;   // 256 thr = 16 rows x 16 h-quads
    float m0 = ms[0][row], m1 = ms[1][row], m2 = ms[2][row], m3 = ms[3][row];
    float mstar = fmaxf(fmaxf(m0, m1), fmaxf(m2, m3));
    float f0 = exp2f(m0 - mstar), f1 = exp2f(m1 - mstar);
    float f2 = exp2f(m2 - mstar), f3 = exp2f(m3 - mstar);
    float inv = 1.0f / (ls[0][row] * f0 + ls[1][row] * f1 +
                        ls[2][row] * f2 + ls[3][row] * f3);
    float4 o;
    o.x = (Om[0][h0 + 0][row] * f0 + Om[1][h0 + 0][row] * f1 +
           Om[2][h0 + 0][row] * f2 + Om[3][h0 + 0][row] * f3) * inv;
    o.y = (Om[0][h0 + 1][row] * f0 + Om[1][h0 + 1][row] * f1 +
           Om[2][h0 + 1][row] * f2 + Om[3][h0 + 1][row] * f3) * inv;
    o.z = (Om[0][h0 + 2][row] * f0 + Om[1][h0 + 2][row] * f1 +
           Om[2][h0 + 2][row] * f2 + Om[3][h0 + 2][row] * f3) * inv;
    o.w = (Om[0][h0 + 3][row] * f0 + Om[1][h0 + 3][row] * f1 +
           Om[2][h0 + 3][row] * f2 + Om[3][h0 + 3][row] * f3) * inv;
    *(float4*)(out + ((long)b * S + qrow0 + row) * H + h0) = o;
  }
}

extern "C" void kernel_launch(void* const* d_in, const int* in_sizes, int n_in,
                              void* d_out, int out_size, void* d_ws, size_t ws_size,
                              hipStream_t stream) {
  const float* x  = (const float*)d_in[0];
  const float* Wq = (const float*)d_in[1];
  const float* Wk = (const float*)d_in[2];
  const float* Wv = (const float*)d_in[3];
  float* outp = (float*)d_out;
  unsigned short* WT3 = (unsigned short*)d_ws;                       // 384 KB
  unsigned short* q  = (unsigned short*)((char*)d_ws + 512 * 1024);  // 2 MB each
  unsigned short* kk = q + (size_t)Bn * S * H;
  unsigned short* vT = kk + (size_t)Bn * S * H;
  wtrans_kernel<<<dim3(48), dim3(256), 0, stream>>>(Wq, Wk, Wv, WT3);
  qkv_kernel<<<dim3((Bn * S) / 32), dim3(256), 0, stream>>>(x, WT3, q, kk, vT);
  attn_kernel<<<dim3(Bn * 128), dim3(256), 0, stream>>>(q, kk, vT, outp);
}